// Round 2
// baseline (526.494 us; speedup 1.0000x reference)
//
#include <hip/hip_runtime.h>

#define DPROJ 1024

// ---------------- pass 0: zero cluster counters (ws is poisoned every call) --
__global__ void k_zero(int* cnt) {
    if (threadIdx.x < 4) cnt[threadIdx.x] = 0;
}

// ---------------- pass 1: bin tokens by cluster -----------------------------
// pack = (tok << 18) | local   (tok < 16384 = 2^14, local < 160000 < 2^18)
// NOTE: must pack/unpack as UNSIGNED — t<<18 overflows int sign bit for t>=8192.
__global__ void k_classify(const int* __restrict__ inp, int n,
                           int* __restrict__ cnt, int* __restrict__ lists) {
    int t = blockIdx.x * 256 + threadIdx.x;
    if (t >= n) return;
    int v = inp[t];
    int c, l;
    if (v < 20000)       { c = 0; l = v; }
    else if (v < 40000)  { c = 1; l = v - 20000; }
    else if (v < 200000) { c = 2; l = v - 40000; }
    else                 { c = 3; l = v - 200000; }
    int pos = atomicAdd(&cnt[c], 1);
    lists[c * n + pos] = (int)(((unsigned)t << 18) | (unsigned)l);
}

// ---------------- pass 2: per-cluster GEMM ----------------------------------
// out[tok, p] = 32 * sum_d emb[local, d] * proj[p, d]
// Tile: TM=64 tokens x TN=128 cols per block (256 threads).
// Micro-tile: 8 tokens x 4 cols per thread (e-reads broadcast in LDS).
template <int K>
__device__ __forceinline__ void gemm_body(
    const int count, const int* __restrict__ list, int n,
    const float* __restrict__ emb, const float* __restrict__ proj,
    float* __restrict__ out, char* smem)
{
    constexpr int KC = (K < 64) ? K : 64;
    constexpr int TM = 64, TN = 128, TNP = TN + 4;  // +4 pad: staging-write conflicts; keeps 16B align

    const int row0 = blockIdx.y * TM;
    if (row0 >= count) return;
    const int col0 = blockIdx.x * TN;

    int*   s_tok = (int*)smem;            // TM
    int*   s_loc = s_tok + TM;            // TM
    float* e_s   = (float*)(s_loc + TM);  // TM*KC
    float* p_s   = e_s + TM * KC;         // KC*TNP (transposed: p_s[k][c])

    const int tid = threadIdx.x;
    if (tid < TM) {
        int r = row0 + tid;
        if (r < count) {
            unsigned pk = (unsigned)list[r];
            s_tok[tid] = (int)(pk >> 18);        // 0..16383, always >= 0
            s_loc[tid] = (int)(pk & 0x3FFFFu);
        } else {
            s_tok[tid] = -1;
            s_loc[tid] = 0;
        }
    }
    __syncthreads();

    const int tr = tid >> 5;   // 0..7 -> token rows tr*8 .. tr*8+7
    const int tc = tid & 31;   // 0..31 -> cols col0 + tc*4 .. +3

    float acc[8][4];
    #pragma unroll
    for (int i = 0; i < 8; ++i)
        #pragma unroll
        for (int j = 0; j < 4; ++j) acc[i][j] = 0.f;

    for (int kb = 0; kb < K; kb += KC) {
        if (kb > 0) __syncthreads();

        // stage E tile: TM x KC floats (coalesced float4 along K)
        #pragma unroll
        for (int it = 0; it < (TM * KC / 4) / 256; ++it) {
            int idx = tid + it * 256;
            int m   = idx / (KC / 4);
            int kq  = idx % (KC / 4);
            float4 v = make_float4(0.f, 0.f, 0.f, 0.f);
            if (s_tok[m] >= 0)
                v = *(const float4*)&emb[(long)s_loc[m] * K + kb + kq * 4];
            *(float4*)&e_s[m * KC + kq * 4] = v;
        }
        // stage P tile transposed: p_s[k][c], c = 0..TN-1
        #pragma unroll
        for (int it = 0; it < (TN * KC / 4) / 256; ++it) {
            int idx = tid + it * 256;
            int p   = idx / (KC / 4);
            int kq  = idx % (KC / 4);
            float4 v = *(const float4*)&proj[(long)(col0 + p) * K + kb + kq * 4];
            p_s[(kq * 4 + 0) * TNP + p] = v.x;
            p_s[(kq * 4 + 1) * TNP + p] = v.y;
            p_s[(kq * 4 + 2) * TNP + p] = v.z;
            p_s[(kq * 4 + 3) * TNP + p] = v.w;
        }
        __syncthreads();

        #pragma unroll
        for (int k = 0; k < KC; k += 4) {
            float pv[4][4];
            #pragma unroll
            for (int kk = 0; kk < 4; ++kk)
                *(float4*)&pv[kk][0] = *(const float4*)&p_s[(k + kk) * TNP + tc * 4];
            #pragma unroll
            for (int i = 0; i < 8; ++i) {
                float ev[4];
                *(float4*)&ev[0] = *(const float4*)&e_s[(tr * 8 + i) * KC + k];
                #pragma unroll
                for (int kk = 0; kk < 4; ++kk)
                    #pragma unroll
                    for (int j = 0; j < 4; ++j)
                        acc[i][j] = fmaf(ev[kk], pv[kk][j], acc[i][j]);
            }
        }
    }

    // epilogue: scale by 32, scatter rows to out
    #pragma unroll
    for (int i = 0; i < 8; ++i) {
        int m = tr * 8 + i;
        int tok = s_tok[m];
        if (tok >= 0) {
            float4 v = make_float4(acc[i][0] * 32.f, acc[i][1] * 32.f,
                                   acc[i][2] * 32.f, acc[i][3] * 32.f);
            *(float4*)&out[(long)tok * DPROJ + col0 + tc * 4] = v;
        }
    }
}

__global__ __launch_bounds__(256) void k_gemm(
    const int* __restrict__ cnt, const int* __restrict__ lists, int n,
    const float* __restrict__ e0, const float* __restrict__ p0,
    const float* __restrict__ e1, const float* __restrict__ p1,
    const float* __restrict__ e2, const float* __restrict__ p2,
    const float* __restrict__ e3, const float* __restrict__ p3,
    float* __restrict__ out)
{
    extern __shared__ char smem[];
    switch (blockIdx.z) {
    case 0: gemm_body<1024>(cnt[0], lists + 0L * n, n, e0, p0, out, smem); break;
    case 1: gemm_body<256>(cnt[1],  lists + 1L * n, n, e1, p1, out, smem); break;
    case 2: gemm_body<64>(cnt[2],   lists + 2L * n, n, e2, p2, out, smem); break;
    case 3: gemm_body<16>(cnt[3],   lists + 3L * n, n, e3, p3, out, smem); break;
    }
}

extern "C" void kernel_launch(void* const* d_in, const int* in_sizes, int n_in,
                              void* d_out, int out_size, void* d_ws, size_t ws_size,
                              hipStream_t stream) {
    const int*   inp = (const int*)d_in[0];
    const float* e0  = (const float*)d_in[1];
    const float* p0  = (const float*)d_in[2];
    const float* e1  = (const float*)d_in[3];
    const float* p1  = (const float*)d_in[4];
    const float* e2  = (const float*)d_in[5];
    const float* p2  = (const float*)d_in[6];
    const float* e3  = (const float*)d_in[7];
    const float* p3  = (const float*)d_in[8];
    float* out = (float*)d_out;
    const int n = in_sizes[0];  // 16384 tokens

    int* cnt   = (int*)d_ws;
    int* lists = cnt + 4;       // 4 lists of n ints each

    k_zero<<<1, 64, 0, stream>>>(cnt);
    k_classify<<<(n + 255) / 256, 256, 0, stream>>>(inp, n, cnt, lists);

    // smem for largest instantiation (KC=64): tok/loc 512B + E 16KB + P 64*132*4
    size_t smem = 2 * 64 * sizeof(int) + 64 * 64 * sizeof(float) + 64 * 132 * sizeof(float);
    dim3 grid(DPROJ / 128, (n + 63) / 64, 4);
    k_gemm<<<grid, 256, smem, stream>>>(cnt, lists, n, e0, p0, e1, p1, e2, p2, e3, p3, out);
}

// Round 3
// 276.607 us; speedup vs baseline: 1.9034x; 1.9034x over previous
//
#include <hip/hip_runtime.h>

#define DPROJ 1024

// ---------------- pass 0: zero cluster counters (ws is poisoned every call) --
__global__ void k_zero(int* cnt) {
    if (threadIdx.x < 4) cnt[threadIdx.x] = 0;
}

// ---------------- pass 1: bin tokens by cluster, wave-aggregated atomics ----
// pack = (tok << 18) | local  (tok < 2^14, local < 160000 < 2^18), UNSIGNED ops.
// One atomicAdd per wave per cluster (<=1024 total) instead of 16384 per-lane
// atomics on 4 hot addresses (which serialized at ~260us in round 2).
__global__ void k_classify(const int* __restrict__ inp, int n,
                           int* __restrict__ cnt, int* __restrict__ lists) {
    int t = blockIdx.x * 256 + threadIdx.x;
    if (t >= n) return;   // n % 256 == 0 in practice; guard harmless
    int v = inp[t];
    int c, l;
    if (v < 20000)       { c = 0; l = v; }
    else if (v < 40000)  { c = 1; l = v - 20000; }
    else if (v < 200000) { c = 2; l = v - 40000; }
    else                 { c = 3; l = v - 200000; }
    unsigned pack = ((unsigned)t << 18) | (unsigned)l;
    int lane = threadIdx.x & 63;
    #pragma unroll
    for (int cc = 0; cc < 4; ++cc) {
        unsigned long long m = __ballot(c == cc);
        if (c == cc) {
            int first = __ffsll(m) - 1;                       // leader lane
            int rank  = __popcll(m & ((1ull << lane) - 1ull)); // my slot within wave
            int base = 0;
            if (lane == first) base = atomicAdd(&cnt[cc], __popcll(m));
            base = __shfl(base, first, 64);
            lists[cc * n + base + rank] = (int)pack;
        }
    }
}

// ---------------- pass 2: all-cluster GEMM, one launch ----------------------
// out[tok, p] = 32 * sum_d emb[local, d] * proj[p, d]
// ONE body, runtime K, fixed KC=16 chunk (divides 1024/256/64/16) -> single
// instantiation, no register blowup. TM=64 tokens x TN=128 cols per block,
// 256 threads, 8x4 micro-tile. blockIdx.z = cluster (all clusters concurrent
// in one launch for load balance).
__global__ __launch_bounds__(256, 4) void k_gemm(
    const int* __restrict__ cnt, const int* __restrict__ lists, int n,
    const float* __restrict__ e0, const float* __restrict__ p0,
    const float* __restrict__ e1, const float* __restrict__ p1,
    const float* __restrict__ e2, const float* __restrict__ p2,
    const float* __restrict__ e3, const float* __restrict__ p3,
    float* __restrict__ out)
{
    constexpr int TM = 64, TN = 128, KC = 16, TNP = TN + 4; // +4 pad, 16B-align kept

    const int z     = blockIdx.z;
    const int count = cnt[z];
    const int row0  = blockIdx.y * TM;
    if (row0 >= count) return;

    const float* emb  = (z == 0) ? e0 : (z == 1) ? e1 : (z == 2) ? e2 : e3;
    const float* proj = (z == 0) ? p0 : (z == 1) ? p1 : (z == 2) ? p2 : p3;
    const int    K    = (z == 0) ? 1024 : (z == 1) ? 256 : (z == 2) ? 64 : 16;
    const int*   list = lists + (long)z * n;
    const int    col0 = blockIdx.x * TN;

    __shared__ int   s_tok[TM];
    __shared__ int   s_loc[TM];
    __shared__ float e_s[TM * KC];     // 4 KB
    __shared__ float p_s[KC * TNP];    // 8.25 KB, transposed: p_s[k][c]

    const int tid = threadIdx.x;
    if (tid < TM) {
        int r = row0 + tid;
        if (r < count) {
            unsigned pk = (unsigned)list[r];
            s_tok[tid] = (int)(pk >> 18);
            s_loc[tid] = (int)(pk & 0x3FFFFu);
        } else { s_tok[tid] = -1; s_loc[tid] = -1; }
    }
    __syncthreads();

    const int tr = tid >> 5;   // 0..7: token rows tr*8..tr*8+7
    const int tc = tid & 31;   // cols col0 + tc*4 .. +3

    // staging roles (fixed per thread)
    const int  em   = tid >> 2;          // E row 0..63
    const int  ekq  = tid & 3;           // k-quad 0..3
    const int  eloc = s_loc[em];         // cached in reg
    const long ebase = (eloc >= 0) ? (long)eloc * K : 0;
    const bool evalid = (eloc >= 0);

    float acc[8][4];
    #pragma unroll
    for (int i = 0; i < 8; ++i)
        #pragma unroll
        for (int j = 0; j < 4; ++j) acc[i][j] = 0.f;

    for (int kb = 0; kb < K; kb += KC) {
        if (kb) __syncthreads();

        // stage E tile: 64 x 16 floats, 1 float4/thread (contiguous LDS write)
        float4 ev4 = make_float4(0.f, 0.f, 0.f, 0.f);
        if (evalid) ev4 = *(const float4*)&emb[ebase + kb + ekq * 4];
        *(float4*)&e_s[em * KC + ekq * 4] = ev4;

        // stage P tile transposed: 128 cols x 16 k, 2 float4/thread
        #pragma unroll
        for (int it = 0; it < 2; ++it) {
            int p = (tid >> 2) + it * 64;
            float4 v = *(const float4*)&proj[(long)(col0 + p) * K + kb + ekq * 4];
            p_s[(ekq * 4 + 0) * TNP + p] = v.x;
            p_s[(ekq * 4 + 1) * TNP + p] = v.y;
            p_s[(ekq * 4 + 2) * TNP + p] = v.z;
            p_s[(ekq * 4 + 3) * TNP + p] = v.w;
        }
        __syncthreads();

        #pragma unroll
        for (int k = 0; k < KC; k += 4) {
            float pv[4][4];
            #pragma unroll
            for (int kk = 0; kk < 4; ++kk)
                *(float4*)&pv[kk][0] = *(const float4*)&p_s[(k + kk) * TNP + tc * 4];
            #pragma unroll
            for (int i = 0; i < 8; ++i) {
                float evr[4];
                *(float4*)&evr[0] = *(const float4*)&e_s[(tr * 8 + i) * KC + k];
                #pragma unroll
                for (int kk = 0; kk < 4; ++kk)
                    #pragma unroll
                    for (int j = 0; j < 4; ++j)
                        acc[i][j] = fmaf(evr[kk], pv[kk][j], acc[i][j]);
            }
        }
    }

    // epilogue: scale by 32, scatter rows to out
    #pragma unroll
    for (int i = 0; i < 8; ++i) {
        int tok = s_tok[tr * 8 + i];
        if (tok >= 0) {
            float4 v = make_float4(acc[i][0] * 32.f, acc[i][1] * 32.f,
                                   acc[i][2] * 32.f, acc[i][3] * 32.f);
            *(float4*)&out[(long)tok * DPROJ + col0 + tc * 4] = v;
        }
    }
}

extern "C" void kernel_launch(void* const* d_in, const int* in_sizes, int n_in,
                              void* d_out, int out_size, void* d_ws, size_t ws_size,
                              hipStream_t stream) {
    const int*   inp = (const int*)d_in[0];
    const float* e0  = (const float*)d_in[1];
    const float* p0  = (const float*)d_in[2];
    const float* e1  = (const float*)d_in[3];
    const float* p1  = (const float*)d_in[4];
    const float* e2  = (const float*)d_in[5];
    const float* p2  = (const float*)d_in[6];
    const float* e3  = (const float*)d_in[7];
    const float* p3  = (const float*)d_in[8];
    float* out = (float*)d_out;
    const int n = in_sizes[0];  // 16384 tokens

    int* cnt   = (int*)d_ws;
    int* lists = cnt + 4;       // 4 lists of n ints each

    k_zero<<<1, 64, 0, stream>>>(cnt);
    k_classify<<<(n + 255) / 256, 256, 0, stream>>>(inp, n, cnt, lists);

    dim3 grid(DPROJ / 128, (n + 63) / 64, 4);
    k_gemm<<<grid, 256, 0, stream>>>(cnt, lists, n, e0, p0, e1, p1, e2, p2, e3, p3, out);
}

// Round 5
// 262.531 us; speedup vs baseline: 2.0055x; 1.0536x over previous
//
#include <hip/hip_runtime.h>
#include <hip/hip_bf16.h>

#define DPROJ 1024

typedef float  f32x4  __attribute__((ext_vector_type(4)));
typedef short  bf16x8 __attribute__((ext_vector_type(8)));

__device__ __forceinline__ unsigned pk2(float a, float b) {
    __hip_bfloat162 h = __float22bfloat162_rn(make_float2(a, b));
    unsigned r; __builtin_memcpy(&r, &h, 4); return r;
}

// ---------------- pass 1: classify via single-block scan (NO global atomics) -
// 1024 threads x 16 tokens. Per-thread 4x16-bit histogram, Hillis-Steele LDS
// inclusive scan, deterministic compact positions. Writes cnt[] itself.
// NOTE: lists are FOUR SEPARATE arrays (lists + c*n); position within each
// list is the per-cluster exclusive rank ONLY (no cross-cluster base!).
__global__ __launch_bounds__(1024) void k_classify(
    const int* __restrict__ inp, int n,
    int* __restrict__ cnt, int* __restrict__ lists)
{
    __shared__ uint2 s[1024];
    const int tid = threadIdx.x;
    const int pt  = (n + 1023) >> 10;   // tokens per thread (16 for n=16384)
    const int t0  = tid * pt;

    int v[16];
    unsigned cp = 0;                    // 2-bit cluster ids, token-major
    uint2 mine = make_uint2(0u, 0u);    // {c0 | c1<<16, c2 | c3<<16}
    for (int j = 0; j < pt; ++j) {
        int t = t0 + j, c = 0;
        if (t < n) {
            int x = inp[t]; v[j] = x;
            c = (x >= 20000) + (x >= 40000) + (x >= 200000);
            if      (c == 0) mine.x += 1u;
            else if (c == 1) mine.x += 1u << 16;
            else if (c == 2) mine.y += 1u;
            else             mine.y += 1u << 16;
        } else v[j] = 0;
        cp |= (unsigned)c << (2 * j);
    }
    s[tid] = mine;
    for (int off = 1; off < 1024; off <<= 1) {
        __syncthreads();
        uint2 add = make_uint2(0u, 0u);
        if (tid >= off) add = s[tid - off];
        __syncthreads();
        s[tid].x += add.x; s[tid].y += add.y;
    }
    __syncthreads();
    uint2 tot = s[1023];
    uint2 inc = s[tid];
    unsigned run[4] = { (inc.x & 0xffffu) - (mine.x & 0xffffu),
                        (inc.x >> 16)     - (mine.x >> 16),
                        (inc.y & 0xffffu) - (mine.y & 0xffffu),
                        (inc.y >> 16)     - (mine.y >> 16) };
    if (tid == 0) {
        cnt[0] = (int)(tot.x & 0xffffu); cnt[1] = (int)(tot.x >> 16);
        cnt[2] = (int)(tot.y & 0xffffu); cnt[3] = (int)(tot.y >> 16);
    }
    const int cut[4] = {0, 20000, 40000, 200000};
    for (int j = 0; j < pt; ++j) {
        int t = t0 + j;
        if (t >= n) break;
        int c = (int)((cp >> (2 * j)) & 3u);
        int l = v[j] - cut[c];
        unsigned pos = run[c]++;                 // per-cluster rank only
        lists[c * n + (int)pos] = (int)(((unsigned)t << 18) | (unsigned)l);
    }
}

// ---------------- pass 2: all-cluster bf16-MFMA GEMM, one launch ------------
// out[tok, p] = 32 * sum_d emb[local, d] * proj[p, d]   (A, B both K-major)
// Block: 256 thr = 4 waves, TM=64 x TN=128 tile, KC=32.
// Wave w: rows [w*16, w*16+16) x all 128 cols -> 8 mfma_f32_16x16x32_bf16 accs.
// LDS tiles bf16, row stride 40 (bank stride 20: only free 2-way aliasing).
__global__ __launch_bounds__(256, 4) void k_gemm(
    const int* __restrict__ cnt, const int* __restrict__ lists, int n,
    const float* __restrict__ e0, const float* __restrict__ p0,
    const float* __restrict__ e1, const float* __restrict__ p1,
    const float* __restrict__ e2, const float* __restrict__ p2,
    const float* __restrict__ e3, const float* __restrict__ p3,
    float* __restrict__ out)
{
    constexpr int TM = 64, TN = 128, KC = 32, STR = 40;

    const int z     = blockIdx.z;
    const int count = cnt[z];
    const int row0  = blockIdx.y * TM;
    if (row0 >= count) return;

    const float* emb  = (z == 0) ? e0 : (z == 1) ? e1 : (z == 2) ? e2 : e3;
    const float* proj = (z == 0) ? p0 : (z == 1) ? p1 : (z == 2) ? p2 : p3;
    const int    K    = (z == 0) ? 1024 : (z == 1) ? 256 : (z == 2) ? 64 : 16;
    const int*   list = lists + (size_t)z * n;
    const int    col0 = blockIdx.x * TN;

    __shared__ int   s_tok[TM];
    __shared__ int   s_loc[TM];
    __shared__ short e_s[TM * STR];   // 5120 B
    __shared__ short p_s[TN * STR];   // 10240 B

    const int tid = threadIdx.x;
    if (tid < TM) {
        int r = row0 + tid;
        if (r < count) {
            unsigned pk = (unsigned)list[r];
            s_tok[tid] = (int)(pk >> 18);
            s_loc[tid] = (int)(pk & 0x3FFFFu);
        } else { s_tok[tid] = -1; s_loc[tid] = -1; }
    }
    __syncthreads();

    // staging roles
    const int  erow = tid >> 2, egrp = tid & 3;
    const int  eloc = s_loc[erow];
    const bool ev   = (eloc >= 0);
    const size_t ebase = ev ? (size_t)eloc * K : 0;

    const int wave = tid >> 6, lane = tid & 63;
    const int lm = lane & 15, quad = lane >> 4;

    f32x4 acc[8];
    #pragma unroll
    for (int i = 0; i < 8; ++i) acc[i] = (f32x4){0.f, 0.f, 0.f, 0.f};

    for (int kb = 0; kb < K; kb += KC) {
        if (kb) __syncthreads();

        // stage E: 64 rows x 32 k (fp32 -> bf16), 8 floats/thread
        {
            float f[8] = {0.f, 0.f, 0.f, 0.f, 0.f, 0.f, 0.f, 0.f};
            int ko = kb + egrp * 8;
            if (ev && ko < K) {
                float4 a = *(const float4*)&emb[ebase + ko];
                float4 b = *(const float4*)&emb[ebase + ko + 4];
                f[0] = a.x; f[1] = a.y; f[2] = a.z; f[3] = a.w;
                f[4] = b.x; f[5] = b.y; f[6] = b.z; f[7] = b.w;
            }
            uint4 q; q.x = pk2(f[0], f[1]); q.y = pk2(f[2], f[3]);
                     q.z = pk2(f[4], f[5]); q.w = pk2(f[6], f[7]);
            *(uint4*)&e_s[erow * STR + egrp * 8] = q;
        }
        // stage P: 128 rows x 32 k, 2 units of 8 floats/thread
        #pragma unroll
        for (int it = 0; it < 2; ++it) {
            int u    = tid + it * 256;
            int prow = u >> 2, pgrp = u & 3;
            int ko   = kb + pgrp * 8;
            float f[8] = {0.f, 0.f, 0.f, 0.f, 0.f, 0.f, 0.f, 0.f};
            if (ko < K) {
                const float* src = &proj[(size_t)(col0 + prow) * K + ko];
                float4 a = *(const float4*)src;
                float4 b = *(const float4*)(src + 4);
                f[0] = a.x; f[1] = a.y; f[2] = a.z; f[3] = a.w;
                f[4] = b.x; f[5] = b.y; f[6] = b.z; f[7] = b.w;
            }
            uint4 q; q.x = pk2(f[0], f[1]); q.y = pk2(f[2], f[3]);
                     q.z = pk2(f[4], f[5]); q.w = pk2(f[6], f[7]);
            *(uint4*)&p_s[prow * STR + pgrp * 8] = q;
        }
        __syncthreads();

        // A frag: row = wave*16 + (lane&15), k = quad*8 + j  (one b128 each)
        bf16x8 af = *(const bf16x8*)&e_s[(wave * 16 + lm) * STR + quad * 8];
        #pragma unroll
        for (int ns = 0; ns < 8; ++ns) {
            bf16x8 bf = *(const bf16x8*)&p_s[(ns * 16 + lm) * STR + quad * 8];
            acc[ns] = __builtin_amdgcn_mfma_f32_16x16x32_bf16(af, bf, acc[ns], 0, 0, 0);
        }
    }

    // epilogue: C/D layout col = lane&15, row = quad*4 + reg (m89-verified)
    int toks[4];
    #pragma unroll
    for (int r = 0; r < 4; ++r) toks[r] = s_tok[wave * 16 + quad * 4 + r];
    #pragma unroll
    for (int ns = 0; ns < 8; ++ns) {
        int col = col0 + ns * 16 + lm;
        #pragma unroll
        for (int r = 0; r < 4; ++r) {
            if (toks[r] >= 0)
                out[(size_t)toks[r] * DPROJ + col] = acc[ns][r] * 32.f;
        }
    }
}

extern "C" void kernel_launch(void* const* d_in, const int* in_sizes, int n_in,
                              void* d_out, int out_size, void* d_ws, size_t ws_size,
                              hipStream_t stream) {
    const int*   inp = (const int*)d_in[0];
    const float* e0  = (const float*)d_in[1];
    const float* p0  = (const float*)d_in[2];
    const float* e1  = (const float*)d_in[3];
    const float* p1  = (const float*)d_in[4];
    const float* e2  = (const float*)d_in[5];
    const float* p2  = (const float*)d_in[6];
    const float* e3  = (const float*)d_in[7];
    const float* p3  = (const float*)d_in[8];
    float* out = (float*)d_out;
    const int n = in_sizes[0];  // 16384 tokens

    int* cnt   = (int*)d_ws;
    int* lists = cnt + 4;       // 4 lists of n ints each

    k_classify<<<1, 1024, 0, stream>>>(inp, n, cnt, lists);

    dim3 grid(DPROJ / 128, (n + 63) / 64, 4);
    k_gemm<<<grid, 256, 0, stream>>>(cnt, lists, n, e0, p0, e1, p1, e2, p2, e3, p3, out);
}